// Round 7
// baseline (67.813 us; speedup 1.0000x reference)
//
#include <hip/hip_runtime.h>

// Fused tanh-RNN (T=64, I=64, H=100) + tanh + linear (C=40), B=16384.
// TRANSPOSED formulation: D = A*B, A = register-resident weight fragments,
// B = data^T (x / h). W_hh/fc_W columns pre-permuted by
//   phi(32kb+8g+e) = 32kb + 16*(e>>2) + 4g + (e&3)
// so MFMA D-output regs ARE the next step's B-fragment after per-lane f16 cvt.
//
// Round-7: 2-way H-SPLIT for occupancy (r2-r6 proved 1 wave/SIMD cannot hide
// its own dependency stalls; ~2450 cyc/step vs ~500 issue-sum). Two waves per
// 16-row tile: role0 = nt 0..3 (h dims 0..63 = B-frag kb 0,1), role1 = nt 4..6
// (kb 2,3). Each wave keeps its OWN kb pair in registers (phi gives D->B free);
// exchanges the foreign pair via 2x ds_write_b128 + 2x ds_read_b128 + ONE raw
// s_barrier per step (double-buffered h). x staged in a per-block LDS ring via
// global_load_lds (3 issues/wave/step, 3 slots ahead); counted vmcnt(6) BEFORE
// each barrier makes both waves' DMA chunks cross-visible. All loop ds ops are
// asm (invisible to LLVM's waitcnt pass -> no vmcnt(0) drains). 2048 waves =
// 2/SIMD; role-parity swap mixes heavy/light waves across SIMDs.

typedef _Float16 half8 __attribute__((ext_vector_type(8)));
typedef float float4_t __attribute__((ext_vector_type(4)));

#define SLOT_BYTES 6144          // 384 chunks x 16B (272 data+pad, rest dummy)
#define RING_BYTES (4 * SLOT_BYTES)
#define HX_BYTES 4096            // one h buffer: 4 kb x 16 c x 4 g x 16B
#define GLOAD16(gp, lp)                                                   \
  __builtin_amdgcn_global_load_lds(                                       \
      (const __attribute__((address_space(1))) void*)(gp),                \
      (__attribute__((address_space(3))) void*)(lp), 16, 0, 0)

__device__ __forceinline__ float tanh_fast(float x) {
  float e = __builtin_amdgcn_exp2f(x * 2.8853900817779268f);
  return 1.0f - 2.0f * __builtin_amdgcn_rcpf(e + 1.0f);
}

template <int NTBASE, int NTN, int FCB, int FCN>
__device__ __forceinline__ void run_tile(
    const float* __restrict__ x, const float* __restrict__ W_ih,
    const float* __restrict__ W_hh, const float* __restrict__ b_ih,
    const float* __restrict__ b_hh, const float* __restrict__ fc_W,
    const float* __restrict__ fc_b, float* __restrict__ out,
    int rowbase, int lane, int wave, char* ldsp)
{
  const int g = lane >> 4;      // k-group / D-row group
  const int c = lane & 15;      // batch col (B,D) == weight row (A)
  constexpr int K0 = NTBASE / 2;     // own kb pair: K0, K0+1
  constexpr int FKB = K0 ^ 2;        // foreign kb pair

  const unsigned ring_base =
      (unsigned)(uintptr_t)(__attribute__((address_space(3))) char*)ldsp;
  const unsigned hx_base = ring_base + RING_BYTES;

  // ---- A-fragment weights, register-resident (this wave's nt range only).
  half8 wih[2][NTN];     // W_ih[16nt+c][32kb+8g+e]
  half8 whh[4][NTN];     // W_hh[16nt+c][phi(32kb+8g+e)]  (all 4 kb, own nts)
  float4_t bias[NTN];    // (b_ih+b_hh)[16nt+4g+v]

  #pragma unroll
  for (int nl = 0; nl < NTN; ++nl) {
    int nt = NTBASE + nl;
    int nb = nt * 16 + 4 * g;
    float4_t bi = {0.f, 0.f, 0.f, 0.f};
    if (nb + 3 < 100) {
      float4_t a = *(const float4_t*)(b_ih + nb);
      float4_t b = *(const float4_t*)(b_hh + nb);
      bi = a + b;
    }
    bias[nl] = bi;

    int nrow = nt * 16 + c;
    bool rv = (nrow < 100);
    #pragma unroll
    for (int kb = 0; kb < 2; ++kb) {
      float4_t f0 = {0.f,0.f,0.f,0.f}, f1 = {0.f,0.f,0.f,0.f};
      if (rv) {
        const float* p = W_ih + nrow * 64 + kb * 32 + g * 8;
        f0 = *(const float4_t*)p;
        f1 = *(const float4_t*)(p + 4);
      }
      half8 h;
      #pragma unroll
      for (int j = 0; j < 4; ++j) { h[j] = (_Float16)f0[j]; h[4 + j] = (_Float16)f1[j]; }
      wih[kb][nl] = h;
    }
    #pragma unroll
    for (int kb = 0; kb < 4; ++kb) {
      int clo = kb * 32 + 4 * g;
      int chi = clo + 16;
      float4_t f0 = {0.f,0.f,0.f,0.f}, f1 = {0.f,0.f,0.f,0.f};
      if (rv && clo + 3 < 100) f0 = *(const float4_t*)(W_hh + nrow * 100 + clo);
      if (rv && chi + 3 < 100) f1 = *(const float4_t*)(W_hh + nrow * 100 + chi);
      half8 h;
      #pragma unroll
      for (int j = 0; j < 4; ++j) { h[j] = (_Float16)f0[j]; h[4 + j] = (_Float16)f1[j]; }
      whh[kb][nl] = h;
    }
  }

  // ---- DMA source pointers: chunk m = j*128 + wave*64 + lane;
  //      row r = m/17, c17 = m%17; c17==16 or m>=272 -> dummy (reads row0 col0,
  //      lands in pad region of the slot -> harmless).
  const float* gsrc[3];
  #pragma unroll
  for (int j = 0; j < 3; ++j) {
    int m = j * 128 + wave * 64 + lane;
    int r = (m * 3856) >> 16;        // m/17 for m<1000
    int c17 = m - r * 17;
    bool valid = (r < 16) & (c17 < 16);
    int row = rowbase + (valid ? r : 0);
    int col = valid ? c17 * 4 : 0;
    gsrc[j] = x + (size_t)row * 4096 + col;
  }

  // ---- prologue: fill slots 0..2 (9 DMA issues/wave); zero own h frags and
  //      publish them to h-buffer 0; vmcnt(6) (slot0 done) + barrier.
  #pragma unroll
  for (int s = 0; s < 3; ++s) {
    char* lb = ldsp + s * SLOT_BYTES + wave * 1024;
    GLOAD16(gsrc[0] + s * 64, lb);
    GLOAD16(gsrc[1] + s * 64, lb + 2048);
    GLOAD16(gsrc[2] + s * 64, lb + 4096);
  }

  half8 own0 = (half8)(_Float16)0.0f;   // B-frag kb K0
  half8 own1 = (half8)(_Float16)0.0f;   // B-frag kb K0+1
  {
    unsigned wa = hx_base + K0 * 1024 + c * 64 + g * 16;   // buffer 0
    asm volatile(
        "ds_write_b128 %0, %1 offset:0\n\t"
        "ds_write_b128 %0, %2 offset:1024"
        :: "v"(wa), "v"(__builtin_bit_cast(float4_t, own0)),
           "v"(__builtin_bit_cast(float4_t, own1)));
  }
  asm volatile("s_waitcnt vmcnt(6) lgkmcnt(0)\n\ts_barrier" ::: "memory");

  float4_t acc[4];

  for (int t = 0; t < 64; ++t) {
    // issue ds_reads: foreign h pair (buf t&1) + x fragment (slot t&3)
    unsigned ha = hx_base + (t & 1) * HX_BYTES + FKB * 1024 + c * 64 + g * 16;
    unsigned xa = ring_base + (t & 3) * SLOT_BYTES + c * 272 + g * 32;
    float4_t fh0, fh1, s0, s1, s2, s3;
    asm volatile(
        "ds_read_b128 %0, %6 offset:0\n\t"
        "ds_read_b128 %1, %6 offset:1024\n\t"
        "ds_read_b128 %2, %7 offset:0\n\t"
        "ds_read_b128 %3, %7 offset:16\n\t"
        "ds_read_b128 %4, %7 offset:128\n\t"
        "ds_read_b128 %5, %7 offset:144"
        : "=&v"(fh0), "=&v"(fh1), "=&v"(s0), "=&v"(s1), "=&v"(s2), "=&v"(s3)
        : "v"(ha), "v"(xa));

    // own-kb recurrence (register-fed; hides ds latency)
    #pragma unroll
    for (int nl = 0; nl < NTN; ++nl) {
      acc[nl] = __builtin_amdgcn_mfma_f32_16x16x32_f16(whh[K0][nl], own0, bias[nl], 0, 0, 0);
      acc[nl] = __builtin_amdgcn_mfma_f32_16x16x32_f16(whh[K0 + 1][nl], own1, acc[nl], 0, 0, 0);
    }

    // wait for ds reads (dataflow-ordered: consumers use post-wait values)
    asm volatile("s_waitcnt lgkmcnt(0)"
                 : "+v"(fh0), "+v"(fh1), "+v"(s0), "+v"(s1), "+v"(s2), "+v"(s3));
    __builtin_amdgcn_sched_barrier(0);

    // foreign-kb recurrence
    half8 fr0 = __builtin_bit_cast(half8, fh0);
    half8 fr1 = __builtin_bit_cast(half8, fh1);
    #pragma unroll
    for (int nl = 0; nl < NTN; ++nl) {
      acc[nl] = __builtin_amdgcn_mfma_f32_16x16x32_f16(whh[FKB][nl], fr0, acc[nl], 0, 0, 0);
      acc[nl] = __builtin_amdgcn_mfma_f32_16x16x32_f16(whh[FKB + 1][nl], fr1, acc[nl], 0, 0, 0);
    }

    // input projection
    half8 xb0, xb1;
    #pragma unroll
    for (int j = 0; j < 4; ++j) {
      xb0[j] = (_Float16)s0[j]; xb0[4 + j] = (_Float16)s1[j];
      xb1[j] = (_Float16)s2[j]; xb1[4 + j] = (_Float16)s3[j];
    }
    #pragma unroll
    for (int nl = 0; nl < NTN; ++nl) {
      acc[nl] = __builtin_amdgcn_mfma_f32_16x16x32_f16(wih[0][nl], xb0, acc[nl], 0, 0, 0);
      acc[nl] = __builtin_amdgcn_mfma_f32_16x16x32_f16(wih[1][nl], xb1, acc[nl], 0, 0, 0);
    }

    // h_{t+1} = tanh(preact); pack own B-frag pair (phi: same-lane)
    #pragma unroll
    for (int nl = 0; nl < NTN; ++nl)
      #pragma unroll
      for (int v = 0; v < 4; ++v)
        acc[nl][v] = tanh_fast(acc[nl][v]);

    #pragma unroll
    for (int v = 0; v < 4; ++v) {
      own0[v]     = (_Float16)acc[0][v];
      own0[4 + v] = (NTN > 1) ? (_Float16)acc[1][v] : (_Float16)0.0f;
      own1[v]     = (NTN > 2) ? (_Float16)acc[2][v] : (_Float16)0.0f;
      own1[4 + v] = (NTN > 3) ? (_Float16)acc[3][v] : (_Float16)0.0f;
    }

    // publish own pair for next step (buffer (t+1)&1)
    unsigned wa = hx_base + ((t + 1) & 1) * HX_BYTES + K0 * 1024 + c * 64 + g * 16;
    asm volatile(
        "ds_write_b128 %0, %1 offset:0\n\t"
        "ds_write_b128 %0, %2 offset:1024"
        :: "v"(wa), "v"(__builtin_bit_cast(float4_t, own0)),
           "v"(__builtin_bit_cast(float4_t, own1)));

    // issue DMA for slot t+3 (clamped source; constant 3 issues/wave/step)
    int tp = t + 3; if (tp > 63) tp = 63;
    char* lb = ldsp + ((t + 3) & 3) * SLOT_BYTES + wave * 1024;
    GLOAD16(gsrc[0] + tp * 64, lb);
    GLOAD16(gsrc[1] + tp * 64, lb + 2048);
    GLOAD16(gsrc[2] + tp * 64, lb + 4096);

    // slot t+1 DMA complete (both waves) + h writes visible, then sync
    asm volatile("s_waitcnt vmcnt(6) lgkmcnt(0)\n\ts_barrier" ::: "memory");
  }

  // ---- epilogue: z = tanh(h_last); out = z @ fc_W^T + fc_b (phi-permuted fc_W)
  #pragma unroll
  for (int nl = 0; nl < NTN; ++nl)
    #pragma unroll
    for (int v = 0; v < 4; ++v)
      acc[nl][v] = tanh_fast(acc[nl][v]);
  #pragma unroll
  for (int v = 0; v < 4; ++v) {
    own0[v]     = (_Float16)acc[0][v];
    own0[4 + v] = (NTN > 1) ? (_Float16)acc[1][v] : (_Float16)0.0f;
    own1[v]     = (NTN > 2) ? (_Float16)acc[2][v] : (_Float16)0.0f;
    own1[4 + v] = (NTN > 3) ? (_Float16)acc[3][v] : (_Float16)0.0f;
  }
  {
    unsigned wa = hx_base + HX_BYTES + K0 * 1024 + c * 64 + g * 16;  // buffer 1
    asm volatile(
        "ds_write_b128 %0, %1 offset:0\n\t"
        "ds_write_b128 %0, %2 offset:1024"
        :: "v"(wa), "v"(__builtin_bit_cast(float4_t, own0)),
           "v"(__builtin_bit_cast(float4_t, own1)));
  }
  asm volatile("s_waitcnt lgkmcnt(0)\n\ts_barrier" ::: "memory");

  float4_t fz0, fz1;
  {
    unsigned ra = hx_base + HX_BYTES + FKB * 1024 + c * 64 + g * 16;
    asm volatile(
        "ds_read_b128 %0, %2 offset:0\n\t"
        "ds_read_b128 %1, %2 offset:1024\n\t"
        "s_waitcnt lgkmcnt(0)"
        : "=&v"(fz0), "=&v"(fz1) : "v"(ra));
  }
  half8 zf[4];
  zf[K0] = own0; zf[K0 + 1] = own1;
  zf[FKB] = __builtin_bit_cast(half8, fz0);
  zf[FKB + 1] = __builtin_bit_cast(half8, fz1);

  // fc weights (this wave's FCN tiles), phi-permuted columns
  half8 wfc[4][FCN];
  float4_t bfc[FCN];
  #pragma unroll
  for (int ft = 0; ft < FCN; ++ft) {
    int fct = FCB + ft;
    int nb = fct * 16 + 4 * g;
    float4_t bi = {0.f,0.f,0.f,0.f};
    if (nb + 3 < 40) bi = *(const float4_t*)(fc_b + nb);
    bfc[ft] = bi;

    int nrow = fct * 16 + c;
    bool rv = (nrow < 40);
    #pragma unroll
    for (int kb = 0; kb < 4; ++kb) {
      int clo = kb * 32 + 4 * g;
      int chi = clo + 16;
      float4_t f0 = {0.f,0.f,0.f,0.f}, f1 = {0.f,0.f,0.f,0.f};
      if (rv && clo + 3 < 100) f0 = *(const float4_t*)(fc_W + nrow * 100 + clo);
      if (rv && chi + 3 < 100) f1 = *(const float4_t*)(fc_W + nrow * 100 + chi);
      half8 h;
      #pragma unroll
      for (int j = 0; j < 4; ++j) { h[j] = (_Float16)f0[j]; h[4 + j] = (_Float16)f1[j]; }
      wfc[kb][ft] = h;
    }
  }

  float4_t oacc[FCN];
  #pragma unroll
  for (int ft = 0; ft < FCN; ++ft) oacc[ft] = bfc[ft];
  #pragma unroll
  for (int kb = 0; kb < 4; ++kb)
    #pragma unroll
    for (int ft = 0; ft < FCN; ++ft)
      oacc[ft] = __builtin_amdgcn_mfma_f32_16x16x32_f16(wfc[kb][ft], zf[kb], oacc[ft], 0, 0, 0);

  // store: lane (g,c) holds out[rowbase+c][n = 16*(FCB+ft)+4g+v]
  #pragma unroll
  for (int ft = 0; ft < FCN; ++ft)
    #pragma unroll
    for (int v = 0; v < 4; ++v) {
      int n = (FCB + ft) * 16 + 4 * g + v;
      if (n < 40)
        out[(size_t)(rowbase + c) * 40 + n] = oacc[ft][v];
    }
}

__global__ __launch_bounds__(128, 2) void rnn_fused(
    const float* __restrict__ x, const float* __restrict__ W_ih,
    const float* __restrict__ W_hh, const float* __restrict__ b_ih,
    const float* __restrict__ b_hh, const float* __restrict__ fc_W,
    const float* __restrict__ fc_b, float* __restrict__ out, int B)
{
  __shared__ char lds[RING_BYTES + 2 * HX_BYTES];
  const int lane = threadIdx.x & 63;
  const int wave = threadIdx.x >> 6;
  const int role = (wave ^ (blockIdx.x & 1)) & 1;   // mix heavy/light across SIMDs
  const int rowbase = blockIdx.x * 16;
  if (rowbase >= B) return;

  if (role == 0)
    run_tile<0, 4, 0, 2>(x, W_ih, W_hh, b_ih, b_hh, fc_W, fc_b, out,
                         rowbase, lane, wave, lds);
  else
    run_tile<4, 3, 2, 1>(x, W_ih, W_hh, b_ih, b_hh, fc_W, fc_b, out,
                         rowbase, lane, wave, lds);
}

extern "C" void kernel_launch(void* const* d_in, const int* in_sizes, int n_in,
                              void* d_out, int out_size, void* d_ws, size_t ws_size,
                              hipStream_t stream) {
  const float* x    = (const float*)d_in[0];
  const float* W_ih = (const float*)d_in[1];
  const float* W_hh = (const float*)d_in[2];
  const float* b_ih = (const float*)d_in[3];
  const float* b_hh = (const float*)d_in[4];
  const float* fc_W = (const float*)d_in[5];
  const float* fc_b = (const float*)d_in[6];
  float* outp = (float*)d_out;

  int B = in_sizes[0] / 4096;      // 16384
  int grid = (B + 15) / 16;        // one 16-row tile per 2-wave block
  rnn_fused<<<grid, 128, 0, stream>>>(x, W_ih, W_hh, b_ih, b_hh, fc_W, fc_b, outp, B);
}

// Round 8
// 65.139 us; speedup vs baseline: 1.0411x; 1.0411x over previous
//
#include <hip/hip_runtime.h>

// Fused tanh-RNN (T=64, I=64, H=100) + tanh + linear (C=40), B=16384.
// TRANSPOSED formulation: D = A*B, A = register-resident weight fragments,
// B = data^T (x / h). W_hh/fc_W columns pre-permuted by
//   phi(32kb+8g+e) = 32kb + 16*(e>>2) + 4g + (e&3)
// so MFMA D-output regs ARE the next step's B-fragment after per-lane f16 cvt.
//
// Round-8: SLAB-RING memory system. r2-r7 all pinned at ~65-68us regardless of
// compute structure; the invariant was the x-read pattern (256B per row per
// step at 16KB stride = granule/request-rate limited, ~4.1 TB/s effective).
// Now each wave stages a 4-step slab (16 rows x 1KB CONTIGUOUS) into a
// double-buffered LDS ring via 16x global_load_lds (1KB fully-coalesced each,
// zero dummy lanes), ONE counted vmcnt(16) per 4 steps, no barriers.
// Row pad 64B (stride 1088) -> ds_read_b128 dword-banks 2-way (free).
// Compute body bit-identical to r6.

typedef _Float16 half8 __attribute__((ext_vector_type(8)));
typedef float float4_t __attribute__((ext_vector_type(4)));

#define ROW_BYTES 1088                  // 1024 data + 64 pad
#define BUF_BYTES (16 * ROW_BYTES)      // 17408 per slab buffer
#define GLOAD16(gp, lp)                                                   \
  __builtin_amdgcn_global_load_lds(                                       \
      (const __attribute__((address_space(1))) void*)(gp),                \
      (__attribute__((address_space(3))) void*)(lp), 16, 0, 0)

__device__ __forceinline__ float tanh_fast(float x) {
  float e = __builtin_amdgcn_exp2f(x * 2.8853900817779268f);
  return 1.0f - 2.0f * __builtin_amdgcn_rcpf(e + 1.0f);
}

// Issue one slab: row j's bytes [slab*1024, slab*1024+1024) -> buf + j*1088.
// Per issue: 64 lanes x 16B = 1KB contiguous global, linear LDS dest.
__device__ __forceinline__ void issue_slab(const float* srcl, int slab, char* buf) {
  const float* s = srcl + slab * 256;
  #pragma unroll
  for (int j = 0; j < 16; ++j) {
    GLOAD16(s, buf + j * ROW_BYTES);
    s += 4096;
  }
}

__global__ __launch_bounds__(64, 1) void rnn_fused(
    const float* __restrict__ x, const float* __restrict__ W_ih,
    const float* __restrict__ W_hh, const float* __restrict__ b_ih,
    const float* __restrict__ b_hh, const float* __restrict__ fc_W,
    const float* __restrict__ fc_b, float* __restrict__ out, int B)
{
  __shared__ char xring[2 * BUF_BYTES];   // 34816 B -> 4 blocks/CU
  const int lane = threadIdx.x & 63;
  const int g = lane >> 4;   // k-group / D-row group
  const int c = lane & 15;   // batch col (B,D) == weight row (A)
  const int rowbase = blockIdx.x * 16;

  // ---- A-fragment weights, register-resident.
  half8 wih[2][7];    // W_ih[16nt+c][32kb+8g+e]
  half8 whh[4][7];    // W_hh[16nt+c][phi(32kb+8g+e)]
  float4_t bias[7];   // (b_ih+b_hh)[16nt+4g+v]

  #pragma unroll
  for (int nt = 0; nt < 7; ++nt) {
    int nb = nt * 16 + 4 * g;
    float4_t bi = {0.f, 0.f, 0.f, 0.f};
    if (nb + 3 < 100) {
      float4_t a = *(const float4_t*)(b_ih + nb);
      float4_t b = *(const float4_t*)(b_hh + nb);
      bi = a + b;
    }
    bias[nt] = bi;

    int nrow = nt * 16 + c;
    bool rv = (nrow < 100);
    #pragma unroll
    for (int kb = 0; kb < 2; ++kb) {
      float4_t f0 = {0.f,0.f,0.f,0.f}, f1 = {0.f,0.f,0.f,0.f};
      if (rv) {
        const float* p = W_ih + nrow * 64 + kb * 32 + g * 8;
        f0 = *(const float4_t*)p;
        f1 = *(const float4_t*)(p + 4);
      }
      half8 h;
      #pragma unroll
      for (int j = 0; j < 4; ++j) { h[j] = (_Float16)f0[j]; h[4 + j] = (_Float16)f1[j]; }
      wih[kb][nt] = h;
    }
    #pragma unroll
    for (int kb = 0; kb < 4; ++kb) {
      int clo = kb * 32 + 4 * g;
      int chi = clo + 16;
      float4_t f0 = {0.f,0.f,0.f,0.f}, f1 = {0.f,0.f,0.f,0.f};
      if (rv && clo + 3 < 100) f0 = *(const float4_t*)(W_hh + nrow * 100 + clo);
      if (rv && chi + 3 < 100) f1 = *(const float4_t*)(W_hh + nrow * 100 + chi);
      half8 h;
      #pragma unroll
      for (int j = 0; j < 4; ++j) { h[j] = (_Float16)f0[j]; h[4 + j] = (_Float16)f1[j]; }
      whh[kb][nt] = h;
    }
  }

  // ---- x slab DMA: lane reads 16B at (row rowbase+j, byte slab*1024 + lane*16)
  const float* srcl = x + (size_t)rowbase * 4096 + lane * 4;

  // prologue: slabs 0,1 -> 32 outstanding
  issue_slab(srcl, 0, xring);
  issue_slab(srcl, 1, xring + BUF_BYTES);

  const unsigned ring_base =
      (unsigned)(uintptr_t)(__attribute__((address_space(3))) char*)xring;
  const unsigned xa0 = ring_base + (unsigned)(c * ROW_BYTES + g * 32);

  float4_t acc[7];
  half8 hfrag[4];
  #pragma unroll
  for (int kb = 0; kb < 4; ++kb) hfrag[kb] = (half8)(_Float16)0.0f;  // h_0 = 0

  for (int grp = 0; grp < 16; ++grp) {
    // slab grp landed once only the 16 newer DMAs remain in flight
    asm volatile("s_waitcnt vmcnt(16)" ::: "memory");
    unsigned xg = xa0 + (unsigned)((grp & 1) * BUF_BYTES);

    #pragma unroll
    for (int t4 = 0; t4 < 4; ++t4) {
      // x fragment for step t = 4*grp + t4 (asm: invisible to waitcnt pass;
      // "memory" clobber keeps the end-of-group DMA issues below these reads)
      unsigned xs = xg + (unsigned)(t4 * 256);
      float4_t s0, s1, s2, s3;
      asm volatile(
          "ds_read_b128 %0, %4 offset:0\n\t"
          "ds_read_b128 %1, %4 offset:16\n\t"
          "ds_read_b128 %2, %4 offset:128\n\t"
          "ds_read_b128 %3, %4 offset:144\n\t"
          "s_waitcnt lgkmcnt(0)"
          : "=&v"(s0), "=&v"(s1), "=&v"(s2), "=&v"(s3)
          : "v"(xs) : "memory");
      __builtin_amdgcn_sched_barrier(0);

      // recurrence first (register-fed)
      #pragma unroll
      for (int nt = 0; nt < 7; ++nt)
        acc[nt] = __builtin_amdgcn_mfma_f32_16x16x32_f16(whh[0][nt], hfrag[0], bias[nt], 0, 0, 0);
      #pragma unroll
      for (int kb = 1; kb < 4; ++kb)
        #pragma unroll
        for (int nt = 0; nt < 7; ++nt)
          acc[nt] = __builtin_amdgcn_mfma_f32_16x16x32_f16(whh[kb][nt], hfrag[kb], acc[nt], 0, 0, 0);

      // input projection
      half8 xb0, xb1;
      #pragma unroll
      for (int j = 0; j < 4; ++j) {
        xb0[j] = (_Float16)s0[j]; xb0[4 + j] = (_Float16)s1[j];
        xb1[j] = (_Float16)s2[j]; xb1[4 + j] = (_Float16)s3[j];
      }
      #pragma unroll
      for (int nt = 0; nt < 7; ++nt) {
        acc[nt] = __builtin_amdgcn_mfma_f32_16x16x32_f16(wih[0][nt], xb0, acc[nt], 0, 0, 0);
        acc[nt] = __builtin_amdgcn_mfma_f32_16x16x32_f16(wih[1][nt], xb1, acc[nt], 0, 0, 0);
      }

      // h_{t+1} = tanh(preact); D regs -> next B-frag via per-lane cvt only
      #pragma unroll
      for (int nt = 0; nt < 7; ++nt)
        #pragma unroll
        for (int v = 0; v < 4; ++v)
          acc[nt][v] = tanh_fast(acc[nt][v]);

      #pragma unroll
      for (int kb = 0; kb < 4; ++kb) {
        half8 h;
        #pragma unroll
        for (int v = 0; v < 4; ++v) {
          h[v] = (_Float16)acc[2 * kb][v];
          h[4 + v] = (kb < 3) ? (_Float16)acc[2 * kb + 1][v] : (_Float16)0.0f;
        }
        hfrag[kb] = h;
      }
    }

    // issue slab grp+2 into the buffer we just finished reading (clamped
    // tail re-issues slab 15 -> keeps the vmcnt cadence constant; lgkm(0)
    // inside each step guarantees all reads of this buffer completed)
    int sl = grp + 2; if (sl > 15) sl = 15;
    issue_slab(srcl, sl, xring + (grp & 1) * BUF_BYTES);
  }

  // ---- epilogue: out^T = fc_W * tanh(h_last)^T + fc_b (phi-permuted fc_W)
  #pragma unroll
  for (int nt = 0; nt < 7; ++nt)
    #pragma unroll
    for (int v = 0; v < 4; ++v)
      acc[nt][v] = tanh_fast(acc[nt][v]);
  #pragma unroll
  for (int kb = 0; kb < 4; ++kb) {
    half8 h;
    #pragma unroll
    for (int v = 0; v < 4; ++v) {
      h[v] = (_Float16)acc[2 * kb][v];
      h[4 + v] = (kb < 3) ? (_Float16)acc[2 * kb + 1][v] : (_Float16)0.0f;
    }
    hfrag[kb] = h;
  }

  half8 wfc[4][3];
  float4_t bfc[3];
  #pragma unroll
  for (int nt = 0; nt < 3; ++nt) {
    int nb = nt * 16 + 4 * g;
    float4_t bi = {0.f,0.f,0.f,0.f};
    if (nb + 3 < 40) bi = *(const float4_t*)(fc_b + nb);
    bfc[nt] = bi;

    int nrow = nt * 16 + c;
    bool rv = (nrow < 40);
    #pragma unroll
    for (int kb = 0; kb < 4; ++kb) {
      int clo = kb * 32 + 4 * g;
      int chi = clo + 16;
      float4_t f0 = {0.f,0.f,0.f,0.f}, f1 = {0.f,0.f,0.f,0.f};
      if (rv && clo + 3 < 100) f0 = *(const float4_t*)(fc_W + nrow * 100 + clo);
      if (rv && chi + 3 < 100) f1 = *(const float4_t*)(fc_W + nrow * 100 + chi);
      half8 h;
      #pragma unroll
      for (int j = 0; j < 4; ++j) { h[j] = (_Float16)f0[j]; h[4 + j] = (_Float16)f1[j]; }
      wfc[kb][nt] = h;
    }
  }

  float4_t oacc[3];
  #pragma unroll
  for (int nt = 0; nt < 3; ++nt) oacc[nt] = bfc[nt];
  #pragma unroll
  for (int kb = 0; kb < 4; ++kb)
    #pragma unroll
    for (int nt = 0; nt < 3; ++nt)
      oacc[nt] = __builtin_amdgcn_mfma_f32_16x16x32_f16(wfc[kb][nt], hfrag[kb], oacc[nt], 0, 0, 0);

  // store: lane (g,c) holds out[rowbase+c][n = 16nt+4g+v]
  #pragma unroll
  for (int nt = 0; nt < 3; ++nt)
    #pragma unroll
    for (int v = 0; v < 4; ++v) {
      int n = nt * 16 + 4 * g + v;
      if (n < 40)
        out[(size_t)(rowbase + c) * 40 + n] = oacc[nt][v];
    }
}

extern "C" void kernel_launch(void* const* d_in, const int* in_sizes, int n_in,
                              void* d_out, int out_size, void* d_ws, size_t ws_size,
                              hipStream_t stream) {
  const float* x    = (const float*)d_in[0];
  const float* W_ih = (const float*)d_in[1];
  const float* W_hh = (const float*)d_in[2];
  const float* b_ih = (const float*)d_in[3];
  const float* b_hh = (const float*)d_in[4];
  const float* fc_W = (const float*)d_in[5];
  const float* fc_b = (const float*)d_in[6];
  float* outp = (float*)d_out;

  int B = in_sizes[0] / 4096;      // 16384
  int grid = (B + 15) / 16;        // one 16-row tile per 1-wave block
  rnn_fused<<<grid, 64, 0, stream>>>(x, W_ih, W_hh, b_ih, b_hh, fc_W, fc_b, outp, B);
}